// Round 7
// baseline (476.421 us; speedup 1.0000x reference)
//
#include <hip/hip_runtime.h>
#include <cstddef>
#include <cstdint>

#define H 128
#define EDIM 16
#define NLAYER 3
#define KU 2304              // 17*128 (16 ea slices + ones) + 128 (h append)
#define NSLICE 18
#define ASTRIDE 2312         // U row stride in ushorts (2304 + 8 pad)
#define NB 256
#define TH 512

typedef unsigned short ushort_t;
typedef unsigned int uint_t;
typedef __attribute__((ext_vector_type(8))) short bf16x8;
typedef __attribute__((ext_vector_type(4))) float f32x4;

__device__ __forceinline__ ushort_t f2bf(float f) {
    uint_t u = __builtin_bit_cast(uint_t, f);
    u += 0x7fffu + ((u >> 16) & 1u);   // RNE
    return (ushort_t)(u >> 16);
}
__device__ __forceinline__ uint_t pack2(float a, float b) {
    return (uint_t)f2bf(a) | ((uint_t)f2bf(b) << 16);
}

struct MP {
    const float *x, *eattr, *node_W, *node_b, *edge_W, *edge_b, *root_W;
    const float *gamma, *beta, *W1, *b1, *W2, *b2;
    const int *src, *dst, *batch;
    int *bar;                 // [0]=cnt, [1]=gen (pre-zeroed by memset node)
    int *offs, *deg, *eord;
    float *cntG, *bnS, *bnQ, *gsum, *h, *xnew, *out;
    ushort_t *Wt2;
    int E, N, G;
};

// agent-scope grid barrier; all NB blocks are co-resident by construction
__device__ __forceinline__ void gbar(int* cnt, int* gen, int mygen)
{
    __syncthreads();
    if (threadIdx.x == 0) {
        __threadfence();   // release: publish this XCD's prior writes
        int prev = __hip_atomic_fetch_add(cnt, 1, __ATOMIC_ACQ_REL,
                                          __HIP_MEMORY_SCOPE_AGENT);
        if (prev == NB - 1) {
            __hip_atomic_store(cnt, 0, __ATOMIC_RELAXED, __HIP_MEMORY_SCOPE_AGENT);
            __hip_atomic_store(gen, mygen, __ATOMIC_RELEASE, __HIP_MEMORY_SCOPE_AGENT);
        } else {
            while (__hip_atomic_load(gen, __ATOMIC_ACQUIRE,
                                     __HIP_MEMORY_SCOPE_AGENT) < mygen)
                __builtin_amdgcn_s_sleep(2);
        }
        __threadfence();   // acquire: invalidate stale lines
    }
    __syncthreads();
}

__global__ __launch_bounds__(TH) void mega(MP p)
{
    alignas(16) __shared__ unsigned char smem[71808];
    const int b = blockIdx.x;
    const int t = threadIdx.x;
    const int N = p.N, E = p.E, G = p.G;

    // =================== phase 0: setup (block-partitioned) ===================
    if (b == 0) {
        // ---- CSR build, LDS-resident ----
        int* sh = (int*)smem;              // [2048]
        int* part = sh + 2048;             // [512]
        for (int i = t; i < N; i += TH) sh[i] = 0;
        __syncthreads();
        for (int e = t; e < E; e += TH) atomicAdd(&sh[p.dst[e]], 1);
        __syncthreads();
        const int base = t * 4;
        int v[4], loc[4], s = 0;
#pragma unroll
        for (int j = 0; j < 4; ++j) v[j] = (base + j < N) ? sh[base + j] : 0;
#pragma unroll
        for (int j = 0; j < 4; ++j) { loc[j] = s; s += v[j]; }
        part[t] = s;
        __syncthreads();
        for (int off = 1; off < TH; off <<= 1) {
            int xp = (t >= off) ? part[t - off] : 0;
            __syncthreads();
            part[t] += xp;
            __syncthreads();
        }
        const int boff = (t == 0) ? 0 : part[t - 1];
#pragma unroll
        for (int j = 0; j < 4; ++j) {
            if (base + j < N) {
                p.deg[base + j] = v[j];
                p.offs[base + j] = boff + loc[j];
            }
        }
        __syncthreads();
#pragma unroll
        for (int j = 0; j < 4; ++j)
            if (base + j < N) sh[base + j] = boff + loc[j];
        __syncthreads();
        for (int e = t; e < E; e += TH) {
            const int d = p.dst[e];
            const int pos = atomicAdd(&sh[d], 1);
            p.eord[pos] = e;
        }
    } else if (b >= 2 && b < 2 + NLAYER * NSLICE) {
        // ---- weight prep: fp32 slice [k=i][o] -> bf16 Wt2[(l*128+o)*KU+s*128+i]
        ushort_t* tile = (ushort_t*)smem;      // [128][136]
        const int bb = b - 2;
        const int l = bb / NSLICE, s = bb % NSLICE;
        const float* S = (s < 16) ? (p.edge_W + ((size_t)l * 16 + s) * (H * H))
                       : (s == 16 ? (p.edge_b + (size_t)l * H * H)
                                  : (p.root_W + (size_t)l * H * H));
        const int k = t >> 2, o0 = (t & 3) * 32;
#pragma unroll
        for (int j = 0; j < 32; j += 4) {
            float4 v = *(const float4*)&S[(size_t)k * H + o0 + j];
            tile[k * 136 + o0 + j + 0] = f2bf(v.x);
            tile[k * 136 + o0 + j + 1] = f2bf(v.y);
            tile[k * 136 + o0 + j + 2] = f2bf(v.z);
            tile[k * 136 + o0 + j + 3] = f2bf(v.w);
        }
        __syncthreads();
        const int n = t >> 2, k0 = (t & 3) * 32;
        ushort_t* outp = p.Wt2 + ((size_t)(l * H + n)) * KU + s * H + k0;
#pragma unroll
        for (int j = 0; j < 32; ++j) outp[j] = tile[(k0 + j) * 136 + n];
    } else if (b >= 64 && b < 96) {
        // ---- node embed: h = x @ node_W + node_b (fp32, K=32), 64 rows/block
        const int m0 = (b - 64) * 64;
        for (int it = 0; it < 16; ++it) {
            const int idx = it * TH + t;           // 0..8191
            const int row = m0 + (idx >> 7), col = idx & 127;
            float acc = p.node_b[col];
#pragma unroll 8
            for (int k = 0; k < 32; ++k)
                acc = fmaf(p.x[(size_t)row * 32 + k], p.node_W[k * H + col], acc);
            p.h[(size_t)row * H + col] = acc;
        }
    } else if (b == 56) {
        // ---- graph-size histogram ----
        int* c = (int*)smem;
        for (int i = t; i < G; i += TH) c[i] = 0;
        __syncthreads();
        for (int v = t; v < N; v += TH) atomicAdd(&c[p.batch[v]], 1);
        __syncthreads();
        for (int i = t; i < G; i += TH) p.cntG[i] = (float)c[i];
    } else if (b == 57) {
        for (int i = t; i < G * H; i += TH) p.gsum[i] = 0.f;
    } else if (b == 58) {
        for (int i = t; i < 2 * NLAYER * H; i += TH) {
            if (i < NLAYER * H) p.bnS[i] = 0.f;
            else p.bnQ[i - NLAYER * H] = 0.f;
        }
    }
    gbar(p.bar, p.bar + 1, 1);

    // =================== layers ===================
    ushort_t* As8 = (ushort_t*)smem;               // 8 * ASTRIDE
    ushort_t* Bs = (ushort_t*)(smem + 8 * ASTRIDE * 2);   // [128][136]
    const int m0 = b * 8;
    const int w = t >> 6;                          // wave 0..7
    const int lane = t & 63;
    const int l15 = lane & 15, quad = lane >> 4;

    for (int l = 0; l < NLAYER; ++l) {
        const ushort_t* Wt2l = p.Wt2 + (size_t)l * H * KU;

        // ---- build: wave w builds U row w (node m0+w) into As8 ----
        {
            const int v = m0 + w;
            const int j = lane;                    // channel pair (2j, 2j+1)
            float u[17][2];
#pragma unroll
            for (int d = 0; d < 17; ++d) { u[d][0] = 0.f; u[d][1] = 0.f; }
            const int st = p.offs[v];
            const int dg = p.deg[v];
            for (int k = 0; k < dg; ++k) {
                const int e = p.eord[st + k];
                const int s = p.src[e];
                const float* eap = p.eattr + (size_t)e * EDIM;
                const float4 w0 = *(const float4*)(eap + 0);
                const float4 w1 = *(const float4*)(eap + 4);
                const float4 w2 = *(const float4*)(eap + 8);
                const float4 w3 = *(const float4*)(eap + 12);
                const float wv[16] = {w0.x, w0.y, w0.z, w0.w, w1.x, w1.y, w1.z, w1.w,
                                      w2.x, w2.y, w2.z, w2.w, w3.x, w3.y, w3.z, w3.w};
                const float2 h2 = *(const float2*)&p.h[(size_t)s * H + 2 * j];
                u[16][0] += h2.x;
                u[16][1] += h2.y;
#pragma unroll
                for (int d = 0; d < 16; ++d) {
                    u[d][0] = fmaf(wv[d], h2.x, u[d][0]);
                    u[d][1] = fmaf(wv[d], h2.y, u[d][1]);
                }
            }
            const float rc = 1.0f / (float)(dg > 0 ? dg : 1);
            uint_t* urow = (uint_t*)&As8[w * ASTRIDE];
#pragma unroll
            for (int d = 0; d < 17; ++d)
                urow[j + d * 64] = pack2(u[d][0] * rc, u[d][1] * rc);
            const float2 hv = *(const float2*)&p.h[(size_t)v * H + 2 * j];
            urow[j + 17 * 64] = pack2(hv.x, hv.y);
        }

        // ---- GEMM: xnew[8,128] = U[8,2304] @ Wt2l^T ----
        f32x4 acc = {0.f, 0.f, 0.f, 0.f};
        const ushort_t* arow = &As8[(l15 & 7) * ASTRIDE];
        for (int c = 0; c < KU / 128; ++c) {
#pragma unroll
            for (int r = 0; r < 4; ++r) {
                const int idx = t + r * TH;
                const int row = idx >> 4, pos = (idx & 15) * 8;
                *(uint4*)&Bs[row * 136 + pos] =
                    *(const uint4*)&Wt2l[(size_t)row * KU + c * 128 + pos];
            }
            __syncthreads();
#pragma unroll
            for (int ks = 0; ks < 4; ++ks) {
                const int k = ks * 32 + quad * 8;
                bf16x8 a = *(const bf16x8*)&arow[c * 128 + k];
                bf16x8 bb = *(const bf16x8*)&Bs[(w * 16 + l15) * 136 + k];
                acc = __builtin_amdgcn_mfma_f32_16x16x32_bf16(a, bb, acc, 0, 0, 0);
            }
            __syncthreads();
        }

        // ---- epilogue: rows m = quad*4+r valid for quad<2; col = w*16+l15
        const int col = w * 16 + l15;
        float s = 0.f, q = 0.f;
        if (quad < 2) {
#pragma unroll
            for (int r = 0; r < 4; ++r) {
                const int m = quad * 4 + r;
                const float val = acc[r];
                p.xnew[(size_t)(m0 + m) * H + col] = val;
                s += val;
                q += val * val;
            }
        }
        s += __shfl_down(s, 16);
        q += __shfl_down(q, 16);
        if (lane < 16) {
            atomicAdd(&p.bnS[l * H + col], s);
            atomicAdd(&p.bnQ[l * H + col], q);
        }
        gbar(p.bar, p.bar + 1, 2 + 2 * l);

        // ---- BN apply on own 8 nodes ----
        {
            const float invN = 1.0f / (float)N;
            const int last = (l == NLAYER - 1);
            for (int i = t; i < 8 * H; i += TH) {
                const int v = m0 + (i >> 7);
                const int c = i & 127;
                const int idx = v * H + c;
                const float mu = p.bnS[l * H + c] * invN;
                const float var = p.bnQ[l * H + c] * invN - mu * mu;
                const float val = (p.xnew[idx] - mu) * rsqrtf(var + 1e-5f)
                                * p.gamma[l * H + c] + p.beta[l * H + c];
                const float hn = p.h[idx] + fmaxf(val, 0.f);
                p.h[idx] = hn;
                if (last) atomicAdd(&p.gsum[p.batch[v] * H + c], hn);
            }
        }
        gbar(p.bar, p.bar + 1, 3 + 2 * l);
    }

    // =================== classifier ===================
    if (b < G && t < 64) {
        const int g = b;
        const int j = t;
        const float rc = 1.0f / fmaxf(p.cntG[g], 1.0f);
        float acc = p.b1[j];
#pragma unroll 8
        for (int i = 0; i < H; ++i)
            acc = fmaf(p.gsum[g * H + i] * rc, p.W1[i * 64 + j], acc);
        float pv = fmaxf(acc, 0.f) * p.W2[j];
#pragma unroll
        for (int off = 32; off > 0; off >>= 1)
            pv += __shfl_down(pv, off);
        if (j == 0) p.out[g] = pv + p.b2[0];
    }
}

extern "C" void kernel_launch(void* const* d_in, const int* in_sizes, int n_in,
                              void* d_out, int out_size, void* d_ws, size_t ws_size,
                              hipStream_t stream)
{
    MP p;
    p.x      = (const float*)d_in[0];
    const int* eidx = (const int*)d_in[1];
    p.eattr  = (const float*)d_in[2];
    p.batch  = (const int*)  d_in[3];
    p.node_W = (const float*)d_in[4];
    p.node_b = (const float*)d_in[5];
    p.edge_W = (const float*)d_in[6];
    p.edge_b = (const float*)d_in[7];
    p.root_W = (const float*)d_in[8];
    p.gamma  = (const float*)d_in[10];
    p.beta   = (const float*)d_in[11];
    p.W1     = (const float*)d_in[12];
    p.b1     = (const float*)d_in[13];
    p.W2     = (const float*)d_in[14];
    p.b2     = (const float*)d_in[15];
    p.out    = (float*)d_out;

    p.N = in_sizes[0] / 32;   // 2048
    p.E = in_sizes[1] / 2;    // 8192
    p.G = out_size;           // 128
    p.src = eidx;
    p.dst = eidx + p.E;

    const int N = p.N, E = p.E, G = p.G;

    // ---- workspace layout ----
    p.bar  = (int*)d_ws;                                   // [4] (memset to 0)
    p.offs = p.bar + 4;                                    // N+16
    p.deg  = p.offs + (N + 16);                            // N
    p.eord = p.deg + N;                                    // E
    p.cntG = (float*)(p.eord + E);                         // G
    p.bnS  = p.cntG + G;                                   // 3*H
    p.bnQ  = p.bnS + NLAYER * H;                           // 3*H
    p.gsum = p.bnQ + NLAYER * H;                           // G*H
    p.h    = p.gsum + (size_t)G * H;                       // N*H
    p.xnew = p.h + (size_t)N * H;                          // N*H
    p.Wt2  = (ushort_t*)(p.xnew + (size_t)N * H);          // 3*128*KU

    hipMemsetAsync(p.bar, 0, 16, stream);
    mega<<<NB, TH, 0, stream>>>(p);
}

// Round 8
// 273.065 us; speedup vs baseline: 1.7447x; 1.7447x over previous
//
#include <hip/hip_runtime.h>
#include <cstddef>
#include <cstdint>

#define H 128
#define EDIM 16
#define NLAYER 3
#define KU 2304              // 17*128 (16 ea slices + ones) + 128 (h append)
#define NSLICE 18
#define ASTRIDE 2312         // U row stride in ushorts (2304 + 8 pad)
#define NB 256
#define TH 512

typedef unsigned short ushort_t;
typedef unsigned int uint_t;
typedef __attribute__((ext_vector_type(8))) short bf16x8;
typedef __attribute__((ext_vector_type(4))) float f32x4;

__device__ __forceinline__ ushort_t f2bf(float f) {
    uint_t u = __builtin_bit_cast(uint_t, f);
    u += 0x7fffu + ((u >> 16) & 1u);   // RNE
    return (ushort_t)(u >> 16);
}
__device__ __forceinline__ uint_t pack2(float a, float b) {
    return (uint_t)f2bf(a) | ((uint_t)f2bf(b) << 16);
}

struct MP {
    const float *x, *eattr, *node_W, *node_b, *edge_W, *edge_b, *root_W;
    const float *gamma, *beta, *W1, *b1, *W2, *b2;
    const int *src, *dst, *batch;
    int *bar;                 // [0]=cnt, [1]=gen (pre-zeroed by memset node)
    int *offs, *deg, *eord;
    float *cntG, *bnS, *bnQ, *gsum, *h0, *out;
    float *xn;                // NLAYER * N*H raw GEMM outputs
    ushort_t *Wt2;
    int E, N, G;
};

// Agent-scope grid barrier with RELAXED polling (no per-iteration L2
// invalidates). Exactly one release fence (wbl2) before arrival and one
// acquire fence (inv) after the generation flips. All NB blocks are
// co-resident by construction (NB == #CUs, LDS fits 1 block/CU).
__device__ __forceinline__ void gbar(int* cnt, int* gen, int mygen)
{
    __syncthreads();
    if (threadIdx.x == 0) {
        __threadfence();   // release: publish prior writes (buffer_wbl2)
        int prev = __hip_atomic_fetch_add(cnt, 1, __ATOMIC_RELAXED,
                                          __HIP_MEMORY_SCOPE_AGENT);
        if (prev == NB - 1) {
            __hip_atomic_store(cnt, 0, __ATOMIC_RELAXED, __HIP_MEMORY_SCOPE_AGENT);
            __hip_atomic_store(gen, mygen, __ATOMIC_RELAXED, __HIP_MEMORY_SCOPE_AGENT);
        } else {
            while (__hip_atomic_load(gen, __ATOMIC_RELAXED,
                                     __HIP_MEMORY_SCOPE_AGENT) < mygen)
                __builtin_amdgcn_s_sleep(8);
        }
        __threadfence();   // acquire: invalidate stale lines (buffer_inv)
    }
    __syncthreads();
}

__global__ __launch_bounds__(TH) void mega(MP p)
{
    alignas(16) __shared__ unsigned char smem[71808];
    const int b = blockIdx.x;
    const int t = threadIdx.x;
    const int N = p.N, E = p.E, G = p.G;

    // =================== phase 0: setup (block-partitioned) ===================
    if (b == 0) {
        // ---- CSR build, LDS-resident ----
        int* sh = (int*)smem;              // [2048]
        int* part = sh + 2048;             // [512]
        for (int i = t; i < N; i += TH) sh[i] = 0;
        __syncthreads();
        for (int e = t; e < E; e += TH) atomicAdd(&sh[p.dst[e]], 1);
        __syncthreads();
        const int base = t * 4;
        int v[4], loc[4], s = 0;
#pragma unroll
        for (int j = 0; j < 4; ++j) v[j] = (base + j < N) ? sh[base + j] : 0;
#pragma unroll
        for (int j = 0; j < 4; ++j) { loc[j] = s; s += v[j]; }
        part[t] = s;
        __syncthreads();
        for (int off = 1; off < TH; off <<= 1) {
            int xp = (t >= off) ? part[t - off] : 0;
            __syncthreads();
            part[t] += xp;
            __syncthreads();
        }
        const int boff = (t == 0) ? 0 : part[t - 1];
#pragma unroll
        for (int j = 0; j < 4; ++j) {
            if (base + j < N) {
                p.deg[base + j] = v[j];
                p.offs[base + j] = boff + loc[j];
            }
        }
        __syncthreads();
#pragma unroll
        for (int j = 0; j < 4; ++j)
            if (base + j < N) sh[base + j] = boff + loc[j];
        __syncthreads();
        for (int e = t; e < E; e += TH) {
            const int d = p.dst[e];
            const int pos = atomicAdd(&sh[d], 1);
            p.eord[pos] = e;
        }
    } else if (b >= 2 && b < 2 + NLAYER * NSLICE) {
        // ---- weight prep: fp32 slice [k=i][o] -> bf16 Wt2[(l*128+o)*KU+s*128+i]
        ushort_t* tile = (ushort_t*)smem;      // [128][136]
        const int bb = b - 2;
        const int l = bb / NSLICE, s = bb % NSLICE;
        const float* S = (s < 16) ? (p.edge_W + ((size_t)l * 16 + s) * (H * H))
                       : (s == 16 ? (p.edge_b + (size_t)l * H * H)
                                  : (p.root_W + (size_t)l * H * H));
        const int k = t >> 2, o0 = (t & 3) * 32;
#pragma unroll
        for (int j = 0; j < 32; j += 4) {
            float4 v = *(const float4*)&S[(size_t)k * H + o0 + j];
            tile[k * 136 + o0 + j + 0] = f2bf(v.x);
            tile[k * 136 + o0 + j + 1] = f2bf(v.y);
            tile[k * 136 + o0 + j + 2] = f2bf(v.z);
            tile[k * 136 + o0 + j + 3] = f2bf(v.w);
        }
        __syncthreads();
        const int n = t >> 2, k0 = (t & 3) * 32;
        ushort_t* outp = p.Wt2 + ((size_t)(l * H + n)) * KU + s * H + k0;
#pragma unroll
        for (int j = 0; j < 32; ++j) outp[j] = tile[(k0 + j) * 136 + n];
    } else if (b >= 64 && b < 96) {
        // ---- node embed: h0 = x @ node_W + node_b (fp32, K=32), 64 rows/block
        const int m0 = (b - 64) * 64;
        for (int it = 0; it < 16; ++it) {
            const int idx = it * TH + t;           // 0..8191
            const int row = m0 + (idx >> 7), col = idx & 127;
            float acc = p.node_b[col];
#pragma unroll 8
            for (int k = 0; k < 32; ++k)
                acc = fmaf(p.x[(size_t)row * 32 + k], p.node_W[k * H + col], acc);
            p.h0[(size_t)row * H + col] = acc;
        }
    } else if (b == 56) {
        // ---- graph-size histogram ----
        int* c = (int*)smem;
        for (int i = t; i < G; i += TH) c[i] = 0;
        __syncthreads();
        for (int v = t; v < N; v += TH) atomicAdd(&c[p.batch[v]], 1);
        __syncthreads();
        for (int i = t; i < G; i += TH) p.cntG[i] = (float)c[i];
    } else if (b == 57) {
        for (int i = t; i < G * H; i += TH) p.gsum[i] = 0.f;
    } else if (b == 58) {
        for (int i = t; i < 2 * NLAYER * H; i += TH) {
            if (i < NLAYER * H) p.bnS[i] = 0.f;
            else p.bnQ[i - NLAYER * H] = 0.f;
        }
    }
    gbar(p.bar, p.bar + 1, 1);

    // =================== layers ===================
    ushort_t* As8 = (ushort_t*)smem;                      // 8 * ASTRIDE
    ushort_t* Bs = (ushort_t*)(smem + 8 * ASTRIDE * 2);   // [128][136]
    float* ab = (float*)Bs;   // per-layer bn scale/shift overlay (build phases)
    const int m0 = b * 8;
    const int w = t >> 6;                                 // wave 0..7
    const int lane = t & 63;
    const int l15 = lane & 15, quad = lane >> 4;
    const float invN = 1.0f / (float)N;

    for (int l = 0; l < NLAYER; ++l) {
        // ---- stage bn coefs a,b for layers j < l (stats final after barrier) --
        if (t < 128 * l) {
            const int j = t >> 7, c = t & 127;
            const float mu = p.bnS[j * H + c] * invN;
            const float var = p.bnQ[j * H + c] * invN - mu * mu;
            const float a = p.gamma[j * H + c] * rsqrtf(var + 1e-5f);
            ab[j * 256 + c] = a;
            ab[j * 256 + 128 + c] = p.beta[j * H + c] - mu * a;
        }
        __syncthreads();

        // ---- build: wave w builds U row w (node m0+w), h recomputed on the fly
        {
            const int v = m0 + w;
            const int j = lane;                    // channel pair (2j, 2j+1)
            float u[17][2];
#pragma unroll
            for (int d = 0; d < 17; ++d) { u[d][0] = 0.f; u[d][1] = 0.f; }
            const int st = p.offs[v];
            const int dg = p.deg[v];
            for (int k = 0; k < dg; ++k) {
                const int e = p.eord[st + k];
                const int s = p.src[e];
                const float* eap = p.eattr + (size_t)e * EDIM;
                const float4 w0 = *(const float4*)(eap + 0);
                const float4 w1 = *(const float4*)(eap + 4);
                const float4 w2 = *(const float4*)(eap + 8);
                const float4 w3 = *(const float4*)(eap + 12);
                const float wv[16] = {w0.x, w0.y, w0.z, w0.w, w1.x, w1.y, w1.z, w1.w,
                                      w2.x, w2.y, w2.z, w2.w, w3.x, w3.y, w3.z, w3.w};
                float2 hv = *(const float2*)&p.h0[(size_t)s * H + 2 * j];
                for (int jj = 0; jj < l; ++jj) {
                    const float2 xv =
                        *(const float2*)&p.xn[((size_t)jj * N + s) * H + 2 * j];
                    hv.x += fmaxf(fmaf(ab[jj * 256 + 2 * j], xv.x,
                                       ab[jj * 256 + 128 + 2 * j]), 0.f);
                    hv.y += fmaxf(fmaf(ab[jj * 256 + 2 * j + 1], xv.y,
                                       ab[jj * 256 + 128 + 2 * j + 1]), 0.f);
                }
                u[16][0] += hv.x;
                u[16][1] += hv.y;
#pragma unroll
                for (int d = 0; d < 16; ++d) {
                    u[d][0] = fmaf(wv[d], hv.x, u[d][0]);
                    u[d][1] = fmaf(wv[d], hv.y, u[d][1]);
                }
            }
            const float rc = 1.0f / (float)(dg > 0 ? dg : 1);
            uint_t* urow = (uint_t*)&As8[w * ASTRIDE];
#pragma unroll
            for (int d = 0; d < 17; ++d)
                urow[j + d * 64] = pack2(u[d][0] * rc, u[d][1] * rc);
            // append column: own h_l row
            float2 hv = *(const float2*)&p.h0[(size_t)v * H + 2 * j];
            for (int jj = 0; jj < l; ++jj) {
                const float2 xv = *(const float2*)&p.xn[((size_t)jj * N + v) * H + 2 * j];
                hv.x += fmaxf(fmaf(ab[jj * 256 + 2 * j], xv.x,
                                   ab[jj * 256 + 128 + 2 * j]), 0.f);
                hv.y += fmaxf(fmaf(ab[jj * 256 + 2 * j + 1], xv.y,
                                   ab[jj * 256 + 128 + 2 * j + 1]), 0.f);
            }
            urow[j + 17 * 64] = pack2(hv.x, hv.y);
        }
        __syncthreads();   // publish As8; protect ab before Bs staging overwrites

        // ---- GEMM: xn_l[8,128] = U[8,2304] @ Wt2l^T ----
        f32x4 acc = {0.f, 0.f, 0.f, 0.f};
        const ushort_t* arow = &As8[(l15 & 7) * ASTRIDE];
        const ushort_t* Wt2l = p.Wt2 + (size_t)l * H * KU;
        for (int c = 0; c < KU / 128; ++c) {
#pragma unroll
            for (int r = 0; r < 4; ++r) {
                const int idx = t + r * TH;
                const int row = idx >> 4, pos = (idx & 15) * 8;
                *(uint4*)&Bs[row * 136 + pos] =
                    *(const uint4*)&Wt2l[(size_t)row * KU + c * 128 + pos];
            }
            __syncthreads();
#pragma unroll
            for (int ks = 0; ks < 4; ++ks) {
                const int k = ks * 32 + quad * 8;
                bf16x8 a = *(const bf16x8*)&arow[c * 128 + k];
                bf16x8 bb = *(const bf16x8*)&Bs[(w * 16 + l15) * 136 + k];
                acc = __builtin_amdgcn_mfma_f32_16x16x32_bf16(a, bb, acc, 0, 0, 0);
            }
            __syncthreads();
        }

        // ---- epilogue: publish raw xn_l rows + BN stats ----
        const int col = w * 16 + l15;
        float s = 0.f, q = 0.f;
        if (quad < 2) {
#pragma unroll
            for (int r = 0; r < 4; ++r) {
                const int m = quad * 4 + r;
                const float val = acc[r];
                p.xn[((size_t)l * N + m0 + m) * H + col] = val;
                s += val;
                q += val * val;
            }
        }
        s += __shfl_down(s, 16);
        q += __shfl_down(q, 16);
        if (lane < 16) {
            atomicAdd(&p.bnS[l * H + col], s);
            atomicAdd(&p.bnQ[l * H + col], q);
        }
        gbar(p.bar, p.bar + 1, 2 + l);
    }

    // =================== final h + global mean pool ===================
    if (t < 128 * NLAYER) {
        const int j = t >> 7, c = t & 127;
        const float mu = p.bnS[j * H + c] * invN;
        const float var = p.bnQ[j * H + c] * invN - mu * mu;
        const float a = p.gamma[j * H + c] * rsqrtf(var + 1e-5f);
        ab[j * 256 + c] = a;
        ab[j * 256 + 128 + c] = p.beta[j * H + c] - mu * a;
    }
    __syncthreads();
    for (int i = t; i < 8 * H; i += TH) {
        const int v = m0 + (i >> 7);
        const int c = i & 127;
        float hv = p.h0[(size_t)v * H + c];
        for (int jj = 0; jj < NLAYER; ++jj)
            hv += fmaxf(fmaf(ab[jj * 256 + c],
                             p.xn[((size_t)jj * N + v) * H + c],
                             ab[jj * 256 + 128 + c]), 0.f);
        atomicAdd(&p.gsum[p.batch[v] * H + c], hv);
    }
    gbar(p.bar, p.bar + 1, 2 + NLAYER);

    // =================== classifier ===================
    if (b < G && t < 64) {
        const int g = b;
        const int j = t;
        const float rc = 1.0f / fmaxf(p.cntG[g], 1.0f);
        float acc = p.b1[j];
#pragma unroll 8
        for (int i = 0; i < H; ++i)
            acc = fmaf(p.gsum[g * H + i] * rc, p.W1[i * 64 + j], acc);
        float pv = fmaxf(acc, 0.f) * p.W2[j];
#pragma unroll
        for (int off = 32; off > 0; off >>= 1)
            pv += __shfl_down(pv, off);
        if (j == 0) p.out[g] = pv + p.b2[0];
    }
}

extern "C" void kernel_launch(void* const* d_in, const int* in_sizes, int n_in,
                              void* d_out, int out_size, void* d_ws, size_t ws_size,
                              hipStream_t stream)
{
    MP p;
    p.x      = (const float*)d_in[0];
    const int* eidx = (const int*)d_in[1];
    p.eattr  = (const float*)d_in[2];
    p.batch  = (const int*)  d_in[3];
    p.node_W = (const float*)d_in[4];
    p.node_b = (const float*)d_in[5];
    p.edge_W = (const float*)d_in[6];
    p.edge_b = (const float*)d_in[7];
    p.root_W = (const float*)d_in[8];
    p.gamma  = (const float*)d_in[10];
    p.beta   = (const float*)d_in[11];
    p.W1     = (const float*)d_in[12];
    p.b1     = (const float*)d_in[13];
    p.W2     = (const float*)d_in[14];
    p.b2     = (const float*)d_in[15];
    p.out    = (float*)d_out;

    p.N = in_sizes[0] / 32;   // 2048
    p.E = in_sizes[1] / 2;    // 8192
    p.G = out_size;           // 128
    p.src = eidx;
    p.dst = eidx + p.E;

    const int N = p.N, E = p.E, G = p.G;

    // ---- workspace layout ----
    p.bar  = (int*)d_ws;                                   // [4] (memset to 0)
    p.offs = p.bar + 4;                                    // N+16
    p.deg  = p.offs + (N + 16);                            // N
    p.eord = p.deg + N;                                    // E
    p.cntG = (float*)(p.eord + E);                         // G
    p.bnS  = p.cntG + G;                                   // 3*H
    p.bnQ  = p.bnS + NLAYER * H;                           // 3*H
    p.gsum = p.bnQ + NLAYER * H;                           // G*H
    p.h0   = p.gsum + (size_t)G * H;                       // N*H
    p.xn   = p.h0 + (size_t)N * H;                         // 3*N*H
    p.Wt2  = (ushort_t*)(p.xn + (size_t)NLAYER * N * H);   // 3*128*KU

    hipMemsetAsync(p.bar, 0, 16, stream);
    mega<<<NB, TH, 0, stream>>>(p);
}